// Round 2
// baseline (14906.372 us; speedup 1.0000x reference)
//
#include <hip/hip_runtime.h>
#include <hip/hip_cooperative_groups.h>

namespace cg = cooperative_groups;

static constexpr int BATCH = 1024;
static constexpr int NIN   = 512;    // in_features
static constexpr int MOUT  = 1024;   // out_features
static constexpr float LAMBD = 0.2f;
static constexpr float TOLF  = 1e-4f;
static constexpr int MAX_ITERS = 100;
static constexpr int MM = BATCH * MOUT;   // 1M elements

// ---------------------------------------------------------------------------
// zero-init: v, u, encoded output, solved flags + counter
// ---------------------------------------------------------------------------
__global__ __launch_bounds__(256) void zero_init(float* v, float* u, float* enc,
                                                 int* solved) {
    int i = blockIdx.x * 256 + threadIdx.x;
    if (i < MM) { v[i] = 0.f; u[i] = 0.f; enc[i] = 0.f; }
    if (i <= BATCH) solved[i] = 0;   // solved[0..1023] flags, solved[1024] = count
}

// ---------------------------------------------------------------------------
// adb = x @ w^T   (1024x512 * (1024x512)^T -> 1024x1024), also beff = adb
// 64x64 tiles, BK=16, 4x4 per thread. stride 68: transposed writes are 2-way
// (68*4 = 272 = 16 mod 32) -> free per m136.
// ---------------------------------------------------------------------------
__global__ __launch_bounds__(256) void gemm_adb(const float* __restrict__ x,
                                                const float* __restrict__ w,
                                                float* __restrict__ adb,
                                                float* __restrict__ beff) {
    __shared__ float As[16][68];
    __shared__ float Bs[16][68];
    const int tid = threadIdx.x;
    const int i0 = (blockIdx.x >> 4) * 64, j0 = (blockIdx.x & 15) * 64;
    const int tx = tid & 15, ty = tid >> 4;
    const int lr = tid >> 2, lk = (tid & 3) << 2;
    float acc[4][4] = {};
    for (int k0 = 0; k0 < NIN; k0 += 16) {
        float4 a4 = *(const float4*)&x[(i0 + lr) * NIN + k0 + lk];
        As[lk + 0][lr] = a4.x; As[lk + 1][lr] = a4.y;
        As[lk + 2][lr] = a4.z; As[lk + 3][lr] = a4.w;
        float4 b4 = *(const float4*)&w[(j0 + lr) * NIN + k0 + lk];  // w[j][k]
        Bs[lk + 0][lr] = b4.x; Bs[lk + 1][lr] = b4.y;
        Bs[lk + 2][lr] = b4.z; Bs[lk + 3][lr] = b4.w;
        __syncthreads();
        #pragma unroll
        for (int kk = 0; kk < 16; ++kk) {
            float4 a_ = *(const float4*)&As[kk][ty << 2];
            float4 b_ = *(const float4*)&Bs[kk][tx << 2];
            acc[0][0] = fmaf(a_.x, b_.x, acc[0][0]);
            acc[0][1] = fmaf(a_.x, b_.y, acc[0][1]);
            acc[0][2] = fmaf(a_.x, b_.z, acc[0][2]);
            acc[0][3] = fmaf(a_.x, b_.w, acc[0][3]);
            acc[1][0] = fmaf(a_.y, b_.x, acc[1][0]);
            acc[1][1] = fmaf(a_.y, b_.y, acc[1][1]);
            acc[1][2] = fmaf(a_.y, b_.z, acc[1][2]);
            acc[1][3] = fmaf(a_.y, b_.w, acc[1][3]);
            acc[2][0] = fmaf(a_.z, b_.x, acc[2][0]);
            acc[2][1] = fmaf(a_.z, b_.y, acc[2][1]);
            acc[2][2] = fmaf(a_.z, b_.z, acc[2][2]);
            acc[2][3] = fmaf(a_.z, b_.w, acc[2][3]);
            acc[3][0] = fmaf(a_.w, b_.x, acc[3][0]);
            acc[3][1] = fmaf(a_.w, b_.y, acc[3][1]);
            acc[3][2] = fmaf(a_.w, b_.z, acc[3][2]);
            acc[3][3] = fmaf(a_.w, b_.w, acc[3][3]);
        }
        __syncthreads();
    }
    #pragma unroll
    for (int r = 0; r < 4; ++r) {
        float4 o = make_float4(acc[r][0], acc[r][1], acc[r][2], acc[r][3]);
        int idx = (i0 + (ty << 2) + r) * MOUT + j0 + (tx << 2);
        *(float4*)&adb[idx]  = o;
        *(float4*)&beff[idx] = o;
    }
}

// ---------------------------------------------------------------------------
// Cooperative ADMM kernel: 256 blocks x 256 threads (1 per CU).
// Phase A: xk = beff @ M_inv.
//   - full path: 64x64 tile, BK=32, double-buffered LDS, reg prefetch,
//     A stored k-major [32][68] (b128 reads, broadcast), B [32][68].
//   - thin path (<=16 active rows in stripe): per-row GEMV, 1 wave/row.
// Phase B: per-row softshrink/norm/convergence/freeze.
// ---------------------------------------------------------------------------
__global__ __launch_bounds__(256, 1)
void admm_kernel(const float* __restrict__ adb, float* beff, float* v, float* u,
                 float* __restrict__ xk, const float* __restrict__ Minv,
                 float* enc, int* solved, int* cnt) {
    cg::grid_group grid = cg::this_grid();
    __shared__ float Ats[2][32][68];   // [buf][k][row]
    __shared__ float Bs [2][32][68];   // [buf][k][col]

    const int tid = threadIdx.x;
    const int bx  = blockIdx.x;
    const int i0 = (bx >> 4) << 6, j0 = (bx & 15) << 6;
    const int tx = tid & 15, ty = tid >> 4;
    const int al_r = tid >> 3, al_k = (tid & 7) << 2;   // A load: rows al_r, al_r+32
    const int bl_k = tid >> 4, bl_j = (tid & 15) << 2;  // B load: k bl_k, bl_k+16
    const int lane = tid & 63;
    const int wv   = tid >> 6;
    const int wrow = (bx << 2) + wv;                    // phase-B row for this wave

    for (int iter = 0; iter < MAX_ITERS; ++iter) {
        // ---- phase A
        unsigned long long done =
            __ballot(((volatile const int*)solved)[i0 + lane] != 0);
        unsigned long long act = ~done;
        int nact = __popcll(act);
        if (nact > 0) {
            if (nact <= 16) {
                // thin path: active rows round-robin over the 4 waves
                for (int q = wv; q < nact; q += 4) {
                    unsigned long long m = act;
                    for (int p = 0; p < q; ++p) m &= m - 1;
                    const int row = i0 + (int)__builtin_ctzll(m);
                    const float* bp = &beff[row << 10];
                    const float* mp = &Minv[j0 + lane];
                    float ac0 = 0.f, ac1 = 0.f, ac2 = 0.f, ac3 = 0.f;
                    #pragma unroll 4
                    for (int k = 0; k < MOUT; k += 4) {
                        ac0 = fmaf(bp[k + 0], mp[(k + 0) << 10], ac0);
                        ac1 = fmaf(bp[k + 1], mp[(k + 1) << 10], ac1);
                        ac2 = fmaf(bp[k + 2], mp[(k + 2) << 10], ac2);
                        ac3 = fmaf(bp[k + 3], mp[(k + 3) << 10], ac3);
                    }
                    xk[(row << 10) + j0 + lane] = (ac0 + ac1) + (ac2 + ac3);
                }
            } else {
                // full 64x64 tile, BK=32, double-buffered
                float acc[4][4] = {};
                float4 an0, an1, bn0, bn1;
                {   // prologue: stage k0 = 0 into buf 0
                    const float* Ab = &beff[(i0 + al_r) * MOUT + al_k];
                    an0 = *(const float4*)Ab;
                    an1 = *(const float4*)(Ab + 32 * MOUT);
                    const float* Bb = &Minv[bl_k * MOUT + j0 + bl_j];
                    bn0 = *(const float4*)Bb;
                    bn1 = *(const float4*)(Bb + 16 * MOUT);
                    Ats[0][al_k + 0][al_r] = an0.x;
                    Ats[0][al_k + 1][al_r] = an0.y;
                    Ats[0][al_k + 2][al_r] = an0.z;
                    Ats[0][al_k + 3][al_r] = an0.w;
                    Ats[0][al_k + 0][al_r + 32] = an1.x;
                    Ats[0][al_k + 1][al_r + 32] = an1.y;
                    Ats[0][al_k + 2][al_r + 32] = an1.z;
                    Ats[0][al_k + 3][al_r + 32] = an1.w;
                    *(float4*)&Bs[0][bl_k][bl_j]      = bn0;
                    *(float4*)&Bs[0][bl_k + 16][bl_j] = bn1;
                }
                __syncthreads();
                #pragma unroll 2
                for (int s = 0; s < 32; ++s) {
                    const int buf = s & 1;
                    if (s < 31) {
                        const int k0 = (s + 1) << 5;
                        const float* Ab = &beff[(i0 + al_r) * MOUT + k0 + al_k];
                        an0 = *(const float4*)Ab;
                        an1 = *(const float4*)(Ab + 32 * MOUT);
                        const float* Bb = &Minv[(k0 + bl_k) * MOUT + j0 + bl_j];
                        bn0 = *(const float4*)Bb;
                        bn1 = *(const float4*)(Bb + 16 * MOUT);
                    }
                    #pragma unroll
                    for (int kk = 0; kk < 32; ++kk) {
                        const float4 a4 = *(const float4*)&Ats[buf][kk][ty << 2];
                        const float4 b4 = *(const float4*)&Bs[buf][kk][tx << 2];
                        acc[0][0] = fmaf(a4.x, b4.x, acc[0][0]);
                        acc[0][1] = fmaf(a4.x, b4.y, acc[0][1]);
                        acc[0][2] = fmaf(a4.x, b4.z, acc[0][2]);
                        acc[0][3] = fmaf(a4.x, b4.w, acc[0][3]);
                        acc[1][0] = fmaf(a4.y, b4.x, acc[1][0]);
                        acc[1][1] = fmaf(a4.y, b4.y, acc[1][1]);
                        acc[1][2] = fmaf(a4.y, b4.z, acc[1][2]);
                        acc[1][3] = fmaf(a4.y, b4.w, acc[1][3]);
                        acc[2][0] = fmaf(a4.z, b4.x, acc[2][0]);
                        acc[2][1] = fmaf(a4.z, b4.y, acc[2][1]);
                        acc[2][2] = fmaf(a4.z, b4.z, acc[2][2]);
                        acc[2][3] = fmaf(a4.z, b4.w, acc[2][3]);
                        acc[3][0] = fmaf(a4.w, b4.x, acc[3][0]);
                        acc[3][1] = fmaf(a4.w, b4.y, acc[3][1]);
                        acc[3][2] = fmaf(a4.w, b4.z, acc[3][2]);
                        acc[3][3] = fmaf(a4.w, b4.w, acc[3][3]);
                    }
                    if (s < 31) {
                        const int nb = buf ^ 1;
                        Ats[nb][al_k + 0][al_r] = an0.x;
                        Ats[nb][al_k + 1][al_r] = an0.y;
                        Ats[nb][al_k + 2][al_r] = an0.z;
                        Ats[nb][al_k + 3][al_r] = an0.w;
                        Ats[nb][al_k + 0][al_r + 32] = an1.x;
                        Ats[nb][al_k + 1][al_r + 32] = an1.y;
                        Ats[nb][al_k + 2][al_r + 32] = an1.z;
                        Ats[nb][al_k + 3][al_r + 32] = an1.w;
                        *(float4*)&Bs[nb][bl_k][bl_j]      = bn0;
                        *(float4*)&Bs[nb][bl_k + 16][bl_j] = bn1;
                    }
                    __syncthreads();
                }
                #pragma unroll
                for (int r = 0; r < 4; ++r) {
                    float4 o = make_float4(acc[r][0], acc[r][1], acc[r][2], acc[r][3]);
                    *(float4*)&xk[(i0 + (ty << 2) + r) * MOUT + j0 + (tx << 2)] = o;
                }
            }
        }
        grid.sync();

        // ---- phase B: per-row update (wave-uniform row)
        if (((volatile const int*)solved)[wrow] == 0) {
            float vn[16];
            float dx2 = 0.f, x2 = 0.f;
            const int rb = wrow * MOUT;
            #pragma unroll
            for (int c = 0; c < 16; ++c) {
                int j = rb + (c << 6) + lane;
                float kx = xk[j];
                float uu = u[j];
                float vv = v[j];
                float t  = kx + uu;
                float av = fabsf(t) - LAMBD;
                float vnew = av > 0.f ? copysignf(av, t) : 0.f;
                float un = uu + kx - vnew;
                float d  = vnew - vv;
                dx2 += d * d;
                x2  += vnew * vnew;
                v[j] = vnew;
                u[j] = un;
                beff[j] = adb[j] + vnew - un;
                vn[c] = vnew;
            }
            #pragma unroll
            for (int off = 32; off; off >>= 1) {
                dx2 += __shfl_xor(dx2, off);
                x2  += __shfl_xor(x2, off);
            }
            // dx/x < TOL  <=>  dx2 < TOL^2 * x2  (x2==0 -> false, matches NaN semantics)
            if (dx2 < TOLF * TOLF * x2) {
                #pragma unroll
                for (int c = 0; c < 16; ++c) enc[rb + (c << 6) + lane] = vn[c];
                if (lane == 0) {
                    ((volatile int*)solved)[wrow] = 1;
                    atomicAdd(cnt, 1);
                }
            }
        }
        grid.sync();
        if (((volatile const int*)cnt)[0] == BATCH) break;
    }
}

// ---------------------------------------------------------------------------
// dec = enc @ w   (1024x1024 * 1024x512 -> 1024x512)
// ---------------------------------------------------------------------------
__global__ __launch_bounds__(256) void gemm_dec(const float* __restrict__ enc,
                                                const float* __restrict__ w,
                                                float* __restrict__ dec) {
    __shared__ float As[16][68];
    __shared__ float Bs[16][68];
    const int tid = threadIdx.x;
    const int i0 = (blockIdx.x >> 3) * 64, j0 = (blockIdx.x & 7) * 64;
    const int tx = tid & 15, ty = tid >> 4;
    const int la_r = tid >> 2, la_k = (tid & 3) << 2;
    const int lb_k = tid >> 4, lb_j = (tid & 15) << 2;
    float acc[4][4] = {};
    for (int k0 = 0; k0 < MOUT; k0 += 16) {
        float4 a4 = *(const float4*)&enc[(i0 + la_r) * MOUT + k0 + la_k];
        As[la_k + 0][la_r] = a4.x; As[la_k + 1][la_r] = a4.y;
        As[la_k + 2][la_r] = a4.z; As[la_k + 3][la_r] = a4.w;
        float4 b4 = *(const float4*)&w[(k0 + lb_k) * NIN + j0 + lb_j];
        *(float4*)&Bs[lb_k][lb_j] = b4;
        __syncthreads();
        #pragma unroll
        for (int kk = 0; kk < 16; ++kk) {
            float4 a_ = *(const float4*)&As[kk][ty << 2];
            float4 b_ = *(const float4*)&Bs[kk][tx << 2];
            acc[0][0] = fmaf(a_.x, b_.x, acc[0][0]);
            acc[0][1] = fmaf(a_.x, b_.y, acc[0][1]);
            acc[0][2] = fmaf(a_.x, b_.z, acc[0][2]);
            acc[0][3] = fmaf(a_.x, b_.w, acc[0][3]);
            acc[1][0] = fmaf(a_.y, b_.x, acc[1][0]);
            acc[1][1] = fmaf(a_.y, b_.y, acc[1][1]);
            acc[1][2] = fmaf(a_.y, b_.z, acc[1][2]);
            acc[1][3] = fmaf(a_.y, b_.w, acc[1][3]);
            acc[2][0] = fmaf(a_.z, b_.x, acc[2][0]);
            acc[2][1] = fmaf(a_.z, b_.y, acc[2][1]);
            acc[2][2] = fmaf(a_.z, b_.z, acc[2][2]);
            acc[2][3] = fmaf(a_.z, b_.w, acc[2][3]);
            acc[3][0] = fmaf(a_.w, b_.x, acc[3][0]);
            acc[3][1] = fmaf(a_.w, b_.y, acc[3][1]);
            acc[3][2] = fmaf(a_.w, b_.z, acc[3][2]);
            acc[3][3] = fmaf(a_.w, b_.w, acc[3][3]);
        }
        __syncthreads();
    }
    #pragma unroll
    for (int r = 0; r < 4; ++r) {
        float4 o = make_float4(acc[r][0], acc[r][1], acc[r][2], acc[r][3]);
        *(float4*)&dec[(i0 + (ty << 2) + r) * NIN + j0 + (tx << 2)] = o;
    }
}

// ---------------------------------------------------------------------------
extern "C" void kernel_launch(void* const* d_in, const int* in_sizes, int n_in,
                              void* d_out, int out_size, void* d_ws, size_t ws_size,
                              hipStream_t stream) {
    const float* x    = (const float*)d_in[0];
    const float* w    = (const float*)d_in[1];
    const float* Minv = (const float*)d_in[2];

    float* enc = (float*)d_out;          // encoded: 1024*1024
    float* dec = enc + MM;               // decoded: 1024*512

    float* ws   = (float*)d_ws;
    float* adb  = ws;                    // 1M
    float* beff = ws + (size_t)MM;       // 1M
    float* v    = ws + 2 * (size_t)MM;   // 1M
    float* u    = ws + 3 * (size_t)MM;   // 1M
    float* xk   = ws + 4 * (size_t)MM;   // 1M
    int* solved = (int*)(ws + 5 * (size_t)MM);  // 1024 flags + 1 counter
    int* cnt    = solved + BATCH;

    zero_init<<<(MM + 255) / 256, 256, 0, stream>>>(v, u, enc, solved);
    gemm_adb<<<256, 256, 0, stream>>>(x, w, adb, beff);

    void* args[] = {(void*)&adb, (void*)&beff, (void*)&v, (void*)&u, (void*)&xk,
                    (void*)&Minv, (void*)&enc, (void*)&solved, (void*)&cnt};
    hipLaunchCooperativeKernel((void*)admm_kernel, dim3(256), dim3(256), args, 0,
                               stream);

    gemm_dec<<<128, 256, 0, stream>>>(enc, w, dec);
}

// Round 3
// 4119.640 us; speedup vs baseline: 3.6184x; 3.6184x over previous
//
#include <hip/hip_runtime.h>

static constexpr int BATCH = 1024;
static constexpr int NIN   = 512;    // in_features
static constexpr int MOUT  = 1024;   // out_features
static constexpr float LAMBD = 0.2f;
static constexpr float TOLF  = 1e-4f;
static constexpr int MAX_ITERS = 100;
static constexpr int MM = BATCH * MOUT;   // 1M elements

// ---------------------------------------------------------------------------
// zero-init: v, u, encoded output, solved flags
// ---------------------------------------------------------------------------
__global__ __launch_bounds__(256) void zero_init(float* v, float* u, float* enc,
                                                 int* solved) {
    int i = blockIdx.x * 256 + threadIdx.x;
    if (i < MM) { v[i] = 0.f; u[i] = 0.f; enc[i] = 0.f; }
    if (i <= BATCH) solved[i] = 0;
}

// ---------------------------------------------------------------------------
// adb = x @ w^T  (1024x512 * (1024x512)^T -> 1024x1024), beff = adb
// 64x64 tiles, BK=16, 4x4 per thread.
// ---------------------------------------------------------------------------
__global__ __launch_bounds__(256) void gemm_adb(const float* __restrict__ x,
                                                const float* __restrict__ w,
                                                float* __restrict__ adb,
                                                float* __restrict__ beff) {
    __shared__ float As[16][68];
    __shared__ float Bs[16][68];
    const int tid = threadIdx.x;
    const int i0 = (blockIdx.x >> 4) * 64, j0 = (blockIdx.x & 15) * 64;
    const int tx = tid & 15, ty = tid >> 4;
    const int lr = tid >> 2, lk = (tid & 3) << 2;
    float acc[4][4] = {};
    for (int k0 = 0; k0 < NIN; k0 += 16) {
        float4 a4 = *(const float4*)&x[(i0 + lr) * NIN + k0 + lk];
        As[lk + 0][lr] = a4.x; As[lk + 1][lr] = a4.y;
        As[lk + 2][lr] = a4.z; As[lk + 3][lr] = a4.w;
        float4 b4 = *(const float4*)&w[(j0 + lr) * NIN + k0 + lk];  // w[j][k]
        Bs[lk + 0][lr] = b4.x; Bs[lk + 1][lr] = b4.y;
        Bs[lk + 2][lr] = b4.z; Bs[lk + 3][lr] = b4.w;
        __syncthreads();
        #pragma unroll
        for (int kk = 0; kk < 16; ++kk) {
            float4 a_ = *(const float4*)&As[kk][ty << 2];
            float4 b_ = *(const float4*)&Bs[kk][tx << 2];
            acc[0][0] = fmaf(a_.x, b_.x, acc[0][0]);
            acc[0][1] = fmaf(a_.x, b_.y, acc[0][1]);
            acc[0][2] = fmaf(a_.x, b_.z, acc[0][2]);
            acc[0][3] = fmaf(a_.x, b_.w, acc[0][3]);
            acc[1][0] = fmaf(a_.y, b_.x, acc[1][0]);
            acc[1][1] = fmaf(a_.y, b_.y, acc[1][1]);
            acc[1][2] = fmaf(a_.y, b_.z, acc[1][2]);
            acc[1][3] = fmaf(a_.y, b_.w, acc[1][3]);
            acc[2][0] = fmaf(a_.z, b_.x, acc[2][0]);
            acc[2][1] = fmaf(a_.z, b_.y, acc[2][1]);
            acc[2][2] = fmaf(a_.z, b_.z, acc[2][2]);
            acc[2][3] = fmaf(a_.z, b_.w, acc[2][3]);
            acc[3][0] = fmaf(a_.w, b_.x, acc[3][0]);
            acc[3][1] = fmaf(a_.w, b_.y, acc[3][1]);
            acc[3][2] = fmaf(a_.w, b_.z, acc[3][2]);
            acc[3][3] = fmaf(a_.w, b_.w, acc[3][3]);
        }
        __syncthreads();
    }
    #pragma unroll
    for (int r = 0; r < 4; ++r) {
        float4 o = make_float4(acc[r][0], acc[r][1], acc[r][2], acc[r][3]);
        int idx = (i0 + (ty << 2) + r) * MOUT + j0 + (tx << 2);
        *(float4*)&adb[idx]  = o;
        *(float4*)&beff[idx] = o;
    }
}

// ---------------------------------------------------------------------------
// One ADMM GEMM step: xkp[c] = beff @ M_inv over K-chunk c (split-K).
// grid = 256*S blocks: tile t = bid&255 (64x64), chunk c = bid>>8 (K = kper).
// Skips tiles whose 64-row stripe is fully solved.
// ---------------------------------------------------------------------------
__global__ __launch_bounds__(256) void gemm_xk(const float* __restrict__ beff,
                                               const float* __restrict__ Minv,
                                               float* __restrict__ xkp,
                                               const int* __restrict__ solved,
                                               int kper) {
    const int bid = blockIdx.x;
    const int t = bid & 255, c = bid >> 8;
    const int i0 = (t >> 4) << 6, j0 = (t & 15) << 6;
    const int tid = threadIdx.x;

    bool done = ((volatile const int*)solved)[i0 + (tid & 63)] != 0;
    if (__ballot(done) == ~0ull) return;   // whole stripe solved

    __shared__ float As[16][68];
    __shared__ float Bs[16][68];
    const int tx = tid & 15, ty = tid >> 4;
    const int lr = tid >> 2, lk = (tid & 3) << 2;   // A load: row lr, k lk..lk+3
    const int bk = tid >> 4, bj = (tid & 15) << 2;  // B load: k bk, col bj..bj+3
    const int kbase = c * kper;
    const int steps = kper >> 4;

    const float* Ap = &beff[(i0 + lr) * MOUT + kbase + lk];
    const float* Bp = &Minv[(size_t)(kbase + bk) * MOUT + j0 + bj];

    float acc[4][4] = {};
    float4 a4 = *(const float4*)Ap;
    float4 b4 = *(const float4*)Bp;
    for (int s = 0; s < steps; ++s) {
        As[lk + 0][lr] = a4.x; As[lk + 1][lr] = a4.y;
        As[lk + 2][lr] = a4.z; As[lk + 3][lr] = a4.w;
        *(float4*)&Bs[bk][bj] = b4;
        __syncthreads();
        if (s + 1 < steps) {
            a4 = *(const float4*)(Ap + (s + 1) * 16);
            b4 = *(const float4*)(Bp + (size_t)(s + 1) * 16 * MOUT);
        }
        #pragma unroll
        for (int kk = 0; kk < 16; ++kk) {
            float4 a_ = *(const float4*)&As[kk][ty << 2];
            float4 b_ = *(const float4*)&Bs[kk][tx << 2];
            acc[0][0] = fmaf(a_.x, b_.x, acc[0][0]);
            acc[0][1] = fmaf(a_.x, b_.y, acc[0][1]);
            acc[0][2] = fmaf(a_.x, b_.z, acc[0][2]);
            acc[0][3] = fmaf(a_.x, b_.w, acc[0][3]);
            acc[1][0] = fmaf(a_.y, b_.x, acc[1][0]);
            acc[1][1] = fmaf(a_.y, b_.y, acc[1][1]);
            acc[1][2] = fmaf(a_.y, b_.z, acc[1][2]);
            acc[1][3] = fmaf(a_.y, b_.w, acc[1][3]);
            acc[2][0] = fmaf(a_.z, b_.x, acc[2][0]);
            acc[2][1] = fmaf(a_.z, b_.y, acc[2][1]);
            acc[2][2] = fmaf(a_.z, b_.z, acc[2][2]);
            acc[2][3] = fmaf(a_.z, b_.w, acc[2][3]);
            acc[3][0] = fmaf(a_.w, b_.x, acc[3][0]);
            acc[3][1] = fmaf(a_.w, b_.y, acc[3][1]);
            acc[3][2] = fmaf(a_.w, b_.z, acc[3][2]);
            acc[3][3] = fmaf(a_.w, b_.w, acc[3][3]);
        }
        __syncthreads();
    }
    float* op = &xkp[(size_t)c * MM + (i0 + (ty << 2)) * MOUT + j0 + (tx << 2)];
    #pragma unroll
    for (int r = 0; r < 4; ++r)
        *(float4*)(op + r * MOUT) =
            make_float4(acc[r][0], acc[r][1], acc[r][2], acc[r][3]);
}

// ---------------------------------------------------------------------------
// Row update: one block per row. Sums split-K partials, softshrink, norms,
// convergence, freeze, beff refresh.
// ---------------------------------------------------------------------------
__global__ __launch_bounds__(256) void update(const float* __restrict__ adb,
                                              const float* __restrict__ xkp,
                                              float* __restrict__ v,
                                              float* __restrict__ u,
                                              float* __restrict__ beff,
                                              float* __restrict__ enc,
                                              int* solved, int S) {
    const int row = blockIdx.x;
    if (((volatile const int*)solved)[row]) return;
    const int tid = threadIdx.x;
    const int rb = (row << 10) + (tid << 2);

    float kx[4] = {0.f, 0.f, 0.f, 0.f};
    for (int c = 0; c < S; ++c) {
        float4 p = *(const float4*)&xkp[(size_t)c * MM + rb];
        kx[0] += p.x; kx[1] += p.y; kx[2] += p.z; kx[3] += p.w;
    }
    float4 u4 = *(const float4*)&u[rb];
    float4 v4 = *(const float4*)&v[rb];
    float4 a4 = *(const float4*)&adb[rb];
    float uu[4] = {u4.x, u4.y, u4.z, u4.w};
    float vv[4] = {v4.x, v4.y, v4.z, v4.w};
    float ab[4] = {a4.x, a4.y, a4.z, a4.w};
    float vn[4], un[4];
    float dx2 = 0.f, x2 = 0.f;
    #pragma unroll
    for (int e = 0; e < 4; ++e) {
        float tt = kx[e] + uu[e];
        float av = fabsf(tt) - LAMBD;
        float vnew = av > 0.f ? copysignf(av, tt) : 0.f;
        un[e] = uu[e] + kx[e] - vnew;
        float d = vnew - vv[e];
        dx2 += d * d;
        x2 += vnew * vnew;
        vn[e] = vnew;
    }
    #pragma unroll
    for (int off = 32; off; off >>= 1) {
        dx2 += __shfl_xor(dx2, off);
        x2  += __shfl_xor(x2, off);
    }
    __shared__ float red[8];
    if ((tid & 63) == 0) { red[tid >> 6] = dx2; red[4 + (tid >> 6)] = x2; }
    __syncthreads();
    dx2 = (red[0] + red[1]) + (red[2] + red[3]);
    x2  = (red[4] + red[5]) + (red[6] + red[7]);

    if (dx2 < TOLF * TOLF * x2) {       // x2==0 -> false (NaN semantics)
        *(float4*)&enc[rb] = make_float4(vn[0], vn[1], vn[2], vn[3]);
        if (tid == 0) ((volatile int*)solved)[row] = 1;
    } else {
        *(float4*)&v[rb] = make_float4(vn[0], vn[1], vn[2], vn[3]);
        *(float4*)&u[rb] = make_float4(un[0], un[1], un[2], un[3]);
        *(float4*)&beff[rb] = make_float4(ab[0] + vn[0] - un[0],
                                          ab[1] + vn[1] - un[1],
                                          ab[2] + vn[2] - un[2],
                                          ab[3] + vn[3] - un[3]);
    }
}

// ---------------------------------------------------------------------------
// dec = enc @ w   (1024x1024 * 1024x512 -> 1024x512)
// ---------------------------------------------------------------------------
__global__ __launch_bounds__(256) void gemm_dec(const float* __restrict__ enc,
                                                const float* __restrict__ w,
                                                float* __restrict__ dec) {
    __shared__ float As[16][68];
    __shared__ float Bs[16][68];
    const int tid = threadIdx.x;
    const int i0 = (blockIdx.x >> 3) * 64, j0 = (blockIdx.x & 7) * 64;
    const int tx = tid & 15, ty = tid >> 4;
    const int la_r = tid >> 2, la_k = (tid & 3) << 2;
    const int lb_k = tid >> 4, lb_j = (tid & 15) << 2;
    float acc[4][4] = {};
    for (int k0 = 0; k0 < MOUT; k0 += 16) {
        float4 a4 = *(const float4*)&enc[(i0 + la_r) * MOUT + k0 + la_k];
        As[la_k + 0][la_r] = a4.x; As[la_k + 1][la_r] = a4.y;
        As[la_k + 2][la_r] = a4.z; As[la_k + 3][la_r] = a4.w;
        float4 b4 = *(const float4*)&w[(k0 + lb_k) * NIN + j0 + lb_j];
        *(float4*)&Bs[lb_k][lb_j] = b4;
        __syncthreads();
        #pragma unroll
        for (int kk = 0; kk < 16; ++kk) {
            float4 a_ = *(const float4*)&As[kk][ty << 2];
            float4 b_ = *(const float4*)&Bs[kk][tx << 2];
            acc[0][0] = fmaf(a_.x, b_.x, acc[0][0]);
            acc[0][1] = fmaf(a_.x, b_.y, acc[0][1]);
            acc[0][2] = fmaf(a_.x, b_.z, acc[0][2]);
            acc[0][3] = fmaf(a_.x, b_.w, acc[0][3]);
            acc[1][0] = fmaf(a_.y, b_.x, acc[1][0]);
            acc[1][1] = fmaf(a_.y, b_.y, acc[1][1]);
            acc[1][2] = fmaf(a_.y, b_.z, acc[1][2]);
            acc[1][3] = fmaf(a_.y, b_.w, acc[1][3]);
            acc[2][0] = fmaf(a_.z, b_.x, acc[2][0]);
            acc[2][1] = fmaf(a_.z, b_.y, acc[2][1]);
            acc[2][2] = fmaf(a_.z, b_.z, acc[2][2]);
            acc[2][3] = fmaf(a_.z, b_.w, acc[2][3]);
            acc[3][0] = fmaf(a_.w, b_.x, acc[3][0]);
            acc[3][1] = fmaf(a_.w, b_.y, acc[3][1]);
            acc[3][2] = fmaf(a_.w, b_.z, acc[3][2]);
            acc[3][3] = fmaf(a_.w, b_.w, acc[3][3]);
        }
        __syncthreads();
    }
    #pragma unroll
    for (int r = 0; r < 4; ++r) {
        float4 o = make_float4(acc[r][0], acc[r][1], acc[r][2], acc[r][3]);
        *(float4*)&dec[(i0 + (ty << 2) + r) * NIN + j0 + (tx << 2)] = o;
    }
}

// ---------------------------------------------------------------------------
extern "C" void kernel_launch(void* const* d_in, const int* in_sizes, int n_in,
                              void* d_out, int out_size, void* d_ws, size_t ws_size,
                              hipStream_t stream) {
    const float* x    = (const float*)d_in[0];
    const float* w    = (const float*)d_in[1];
    const float* Minv = (const float*)d_in[2];

    float* enc = (float*)d_out;          // encoded: 1024*1024
    float* dec = enc + MM;               // decoded: 1024*512

    float* ws   = (float*)d_ws;
    float* adb  = ws;                    // 1M
    float* beff = ws + (size_t)MM;       // 1M
    float* v    = ws + 2 * (size_t)MM;   // 1M
    float* u    = ws + 3 * (size_t)MM;   // 1M
    float* xkp  = ws + 4 * (size_t)MM;   // S * 1M partials

    // pick split-K factor by available workspace (constant across calls)
    int S = 1;
    if (ws_size >= (size_t)(4 + 4) * MM * 4 + 8192) S = 4;
    else if (ws_size >= (size_t)(4 + 2) * MM * 4 + 8192) S = 2;
    int kper = MOUT / S;

    int* solved = (int*)(xkp + (size_t)S * MM);

    zero_init<<<(MM + 255) / 256, 256, 0, stream>>>(v, u, enc, solved);
    gemm_adb<<<256, 256, 0, stream>>>(x, w, adb, beff);

    for (int it = 0; it < MAX_ITERS; ++it) {
        gemm_xk<<<256 * S, 256, 0, stream>>>(beff, Minv, xkp, solved, kper);
        update<<<BATCH, 256, 0, stream>>>(adb, xkp, v, u, beff, enc, solved, S);
    }

    gemm_dec<<<128, 256, 0, stream>>>(enc, w, dec);
}

// Round 4
// 2301.865 us; speedup vs baseline: 6.4758x; 1.7897x over previous
//
#include <hip/hip_runtime.h>

typedef _Float16 half8 __attribute__((ext_vector_type(8)));
typedef _Float16 half4 __attribute__((ext_vector_type(4)));
typedef float floatx4 __attribute__((ext_vector_type(4)));

static constexpr int BATCH = 1024;
static constexpr int NIN   = 512;    // in_features
static constexpr int MOUT  = 1024;   // out_features
static constexpr float LAMBD = 0.2f;
static constexpr float TOLF  = 1e-4f;
static constexpr int MAX_ITERS = 100;
static constexpr int MM = BATCH * MOUT;   // 1M elements
static constexpr int LDA = 40;            // LDS row stride in halves (80 B)

// ---------------------------------------------------------------------------
// zero-init: v, u, encoded output, solved flags
// ---------------------------------------------------------------------------
__global__ __launch_bounds__(256) void zero_init(float* v, float* u, float* enc,
                                                 int* solved) {
    int i = blockIdx.x * 256 + threadIdx.x;
    if (i < MM) { v[i] = 0.f; u[i] = 0.f; enc[i] = 0.f; }
    if (i <= BATCH) solved[i] = 0;
}

// ---------------------------------------------------------------------------
// MinvT_h/l[n][k] = split_f16(Minv[k][n]) — transpose + 2-term f16 split.
// 64x64 tiles via LDS.
// ---------------------------------------------------------------------------
__global__ __launch_bounds__(256) void split_minv(const float* __restrict__ Minv,
                                                  _Float16* __restrict__ Th,
                                                  _Float16* __restrict__ Tl) {
    __shared__ float T[64][65];
    const int tid = threadIdx.x;
    const int k0 = (blockIdx.x >> 4) << 6, n0 = (blockIdx.x & 15) << 6;
    const int r = tid >> 4, c4 = (tid & 15) << 2;
    #pragma unroll
    for (int p = 0; p < 4; ++p) {
        float4 v4 = *(const float4*)&Minv[(k0 + r + p * 16) * MOUT + n0 + c4];
        T[r + p * 16][c4 + 0] = v4.x;
        T[r + p * 16][c4 + 1] = v4.y;
        T[r + p * 16][c4 + 2] = v4.z;
        T[r + p * 16][c4 + 3] = v4.w;
    }
    __syncthreads();
    #pragma unroll
    for (int p = 0; p < 4; ++p) {
        const int n = r + p * 16;
        half4 h, l;
        #pragma unroll
        for (int i = 0; i < 4; ++i) {
            float val = T[c4 + i][n];
            _Float16 hh = (_Float16)val;
            h[i] = hh;
            l[i] = (_Float16)(val - (float)hh);
        }
        size_t o = (size_t)(n0 + n) * MOUT + k0 + c4;
        *(half4*)&Th[o] = h;
        *(half4*)&Tl[o] = l;
    }
}

// ---------------------------------------------------------------------------
// adb = x @ w^T  (fp32, runs once). Epilogue also emits beff_h/l = split(adb).
// ---------------------------------------------------------------------------
__global__ __launch_bounds__(256) void gemm_adb(const float* __restrict__ x,
                                                const float* __restrict__ w,
                                                float* __restrict__ adb,
                                                _Float16* __restrict__ bh,
                                                _Float16* __restrict__ bl) {
    __shared__ float As[16][68];
    __shared__ float Bs[16][68];
    const int tid = threadIdx.x;
    const int i0 = (blockIdx.x >> 4) * 64, j0 = (blockIdx.x & 15) * 64;
    const int tx = tid & 15, ty = tid >> 4;
    const int lr = tid >> 2, lk = (tid & 3) << 2;
    float acc[4][4] = {};
    for (int k0 = 0; k0 < NIN; k0 += 16) {
        float4 a4 = *(const float4*)&x[(i0 + lr) * NIN + k0 + lk];
        As[lk + 0][lr] = a4.x; As[lk + 1][lr] = a4.y;
        As[lk + 2][lr] = a4.z; As[lk + 3][lr] = a4.w;
        float4 b4 = *(const float4*)&w[(j0 + lr) * NIN + k0 + lk];
        Bs[lk + 0][lr] = b4.x; Bs[lk + 1][lr] = b4.y;
        Bs[lk + 2][lr] = b4.z; Bs[lk + 3][lr] = b4.w;
        __syncthreads();
        #pragma unroll
        for (int kk = 0; kk < 16; ++kk) {
            float4 a_ = *(const float4*)&As[kk][ty << 2];
            float4 b_ = *(const float4*)&Bs[kk][tx << 2];
            #pragma unroll
            for (int r = 0; r < 4; ++r) {
                float av = r == 0 ? a_.x : r == 1 ? a_.y : r == 2 ? a_.z : a_.w;
                acc[r][0] = fmaf(av, b_.x, acc[r][0]);
                acc[r][1] = fmaf(av, b_.y, acc[r][1]);
                acc[r][2] = fmaf(av, b_.z, acc[r][2]);
                acc[r][3] = fmaf(av, b_.w, acc[r][3]);
            }
        }
        __syncthreads();
    }
    #pragma unroll
    for (int r = 0; r < 4; ++r) {
        size_t idx = (size_t)(i0 + (ty << 2) + r) * MOUT + j0 + (tx << 2);
        *(float4*)&adb[idx] =
            make_float4(acc[r][0], acc[r][1], acc[r][2], acc[r][3]);
        half4 h, l;
        #pragma unroll
        for (int e = 0; e < 4; ++e) {
            _Float16 hh = (_Float16)acc[r][e];
            h[e] = hh;
            l[e] = (_Float16)(acc[r][e] - (float)hh);
        }
        *(half4*)&bh[idx] = h;
        *(half4*)&bl[idx] = l;
    }
}

// ---------------------------------------------------------------------------
// Iteration GEMM: xkp[c] = beff @ Minv over K-chunk c, split-f16 MFMA.
// xk = Ah*Bh + Ah*Bl + Al*Bh (fp32 acc), rel err ~2^-22.
// Block: 64x64 tile, 4 waves (2x2), each wave 2x2 of 16x16x32 MFMA tiles.
// ---------------------------------------------------------------------------
__global__ __launch_bounds__(256) void gemm_xk(const _Float16* __restrict__ bh,
                                               const _Float16* __restrict__ bl,
                                               const _Float16* __restrict__ Th,
                                               const _Float16* __restrict__ Tl,
                                               float* __restrict__ xkp,
                                               const int* __restrict__ solved,
                                               int kper) {
    const int bid = blockIdx.x;
    const int t = bid & 255, c = bid >> 8;
    const int m0 = (t >> 4) << 6, n0 = (t & 15) << 6;
    const int tid = threadIdx.x;

    bool done = ((volatile const int*)solved)[m0 + (tid & 63)] != 0;
    if (__ballot(done) == ~0ull) return;   // whole 64-row stripe solved

    __shared__ _Float16 Ah[64 * LDA];
    __shared__ _Float16 Al[64 * LDA];
    __shared__ _Float16 Bh[64 * LDA];
    __shared__ _Float16 Bl[64 * LDA];

    const int srow = tid >> 2;            // staging row/col 0..63
    const int skof = (tid & 3) << 3;      // staging k offset 0,8,16,24
    const int kbase = c * kper;
    const int steps = kper >> 5;          // BK=32

    const size_t gA = (size_t)(m0 + srow) * MOUT + kbase + skof;
    const size_t gB = (size_t)(n0 + srow) * MOUT + kbase + skof;
    const int lds_off = srow * LDA + skof;

    const int lane = tid & 63;
    const int wm = (tid >> 7) & 1, wn = (tid >> 6) & 1;
    const int fr = lane & 15;             // frag row/col within 16
    const int kq = (lane >> 4) << 3;      // frag k offset 0,8,16,24
    const int arow0 = (wm << 5) + fr, arow1 = arow0 + 16;
    const int bcol0 = (wn << 5) + fr, bcol1 = bcol0 + 16;

    floatx4 acc[2][2] = {};
    half8 rah, ral, rbh, rbl;
    rah = *(const half8*)&bh[gA];
    ral = *(const half8*)&bl[gA];
    rbh = *(const half8*)&Th[gB];
    rbl = *(const half8*)&Tl[gB];

    for (int s = 0; s < steps; ++s) {
        *(half8*)&Ah[lds_off] = rah;
        *(half8*)&Al[lds_off] = ral;
        *(half8*)&Bh[lds_off] = rbh;
        *(half8*)&Bl[lds_off] = rbl;
        __syncthreads();
        if (s + 1 < steps) {
            const int ko = (s + 1) << 5;
            rah = *(const half8*)&bh[gA + ko];
            ral = *(const half8*)&bl[gA + ko];
            rbh = *(const half8*)&Th[gB + ko];
            rbl = *(const half8*)&Tl[gB + ko];
        }
        // fragment loads (ds_read_b128 each)
        half8 a_h0 = *(const half8*)&Ah[arow0 * LDA + kq];
        half8 a_h1 = *(const half8*)&Ah[arow1 * LDA + kq];
        half8 a_l0 = *(const half8*)&Al[arow0 * LDA + kq];
        half8 a_l1 = *(const half8*)&Al[arow1 * LDA + kq];
        half8 b_h0 = *(const half8*)&Bh[bcol0 * LDA + kq];
        half8 b_h1 = *(const half8*)&Bh[bcol1 * LDA + kq];
        half8 b_l0 = *(const half8*)&Bl[bcol0 * LDA + kq];
        half8 b_l1 = *(const half8*)&Bl[bcol1 * LDA + kq];

        acc[0][0] = __builtin_amdgcn_mfma_f32_16x16x32_f16(a_h0, b_l0, acc[0][0], 0, 0, 0);
        acc[0][0] = __builtin_amdgcn_mfma_f32_16x16x32_f16(a_l0, b_h0, acc[0][0], 0, 0, 0);
        acc[0][0] = __builtin_amdgcn_mfma_f32_16x16x32_f16(a_h0, b_h0, acc[0][0], 0, 0, 0);
        acc[0][1] = __builtin_amdgcn_mfma_f32_16x16x32_f16(a_h0, b_l1, acc[0][1], 0, 0, 0);
        acc[0][1] = __builtin_amdgcn_mfma_f32_16x16x32_f16(a_l0, b_h1, acc[0][1], 0, 0, 0);
        acc[0][1] = __builtin_amdgcn_mfma_f32_16x16x32_f16(a_h0, b_h1, acc[0][1], 0, 0, 0);
        acc[1][0] = __builtin_amdgcn_mfma_f32_16x16x32_f16(a_h1, b_l0, acc[1][0], 0, 0, 0);
        acc[1][0] = __builtin_amdgcn_mfma_f32_16x16x32_f16(a_l1, b_h0, acc[1][0], 0, 0, 0);
        acc[1][0] = __builtin_amdgcn_mfma_f32_16x16x32_f16(a_h1, b_h0, acc[1][0], 0, 0, 0);
        acc[1][1] = __builtin_amdgcn_mfma_f32_16x16x32_f16(a_h1, b_l1, acc[1][1], 0, 0, 0);
        acc[1][1] = __builtin_amdgcn_mfma_f32_16x16x32_f16(a_l1, b_h1, acc[1][1], 0, 0, 0);
        acc[1][1] = __builtin_amdgcn_mfma_f32_16x16x32_f16(a_h1, b_h1, acc[1][1], 0, 0, 0);
        __syncthreads();
    }

    // C/D layout: col = lane&15, row = (lane>>4)*4 + reg  [m89 verified]
    float* op = &xkp[(size_t)c * MM];
    const int orow = (lane >> 4) << 2;
    #pragma unroll
    for (int g = 0; g < 2; ++g) {
        const int gr = m0 + (wm << 5) + (g << 4) + orow;
        #pragma unroll
        for (int h = 0; h < 2; ++h) {
            const int gc = n0 + (wn << 5) + (h << 4) + (lane & 15);
            #pragma unroll
            for (int r = 0; r < 4; ++r)
                op[(size_t)(gr + r) * MOUT + gc] = acc[g][h][r];
        }
    }
}

// ---------------------------------------------------------------------------
// Row update: sums split-K partials, softshrink, norms, convergence, freeze.
// Emits beff_h/l (split f16) for the next iteration's MFMA GEMM.
// ---------------------------------------------------------------------------
__global__ __launch_bounds__(256) void update(const float* __restrict__ adb,
                                              const float* __restrict__ xkp,
                                              float* __restrict__ v,
                                              float* __restrict__ u,
                                              _Float16* __restrict__ bh,
                                              _Float16* __restrict__ bl,
                                              float* __restrict__ enc,
                                              int* solved, int S) {
    const int row = blockIdx.x;
    if (((volatile const int*)solved)[row]) return;
    const int tid = threadIdx.x;
    const int rb = (row << 10) + (tid << 2);

    float kx[4] = {0.f, 0.f, 0.f, 0.f};
    for (int c = 0; c < S; ++c) {
        float4 p = *(const float4*)&xkp[(size_t)c * MM + rb];
        kx[0] += p.x; kx[1] += p.y; kx[2] += p.z; kx[3] += p.w;
    }
    float4 u4 = *(const float4*)&u[rb];
    float4 v4 = *(const float4*)&v[rb];
    float4 a4 = *(const float4*)&adb[rb];
    float uu[4] = {u4.x, u4.y, u4.z, u4.w};
    float vv[4] = {v4.x, v4.y, v4.z, v4.w};
    float ab[4] = {a4.x, a4.y, a4.z, a4.w};
    float vn[4], un[4];
    float dx2 = 0.f, x2 = 0.f;
    #pragma unroll
    for (int e = 0; e < 4; ++e) {
        float tt = kx[e] + uu[e];
        float av = fabsf(tt) - LAMBD;
        float vnew = av > 0.f ? copysignf(av, tt) : 0.f;
        un[e] = uu[e] + kx[e] - vnew;
        float d = vnew - vv[e];
        dx2 += d * d;
        x2 += vnew * vnew;
        vn[e] = vnew;
    }
    #pragma unroll
    for (int off = 32; off; off >>= 1) {
        dx2 += __shfl_xor(dx2, off);
        x2  += __shfl_xor(x2, off);
    }
    __shared__ float red[8];
    if ((tid & 63) == 0) { red[tid >> 6] = dx2; red[4 + (tid >> 6)] = x2; }
    __syncthreads();
    dx2 = (red[0] + red[1]) + (red[2] + red[3]);
    x2  = (red[4] + red[5]) + (red[6] + red[7]);

    if (dx2 < TOLF * TOLF * x2) {       // x2==0 -> false (NaN semantics)
        *(float4*)&enc[rb] = make_float4(vn[0], vn[1], vn[2], vn[3]);
        if (tid == 0) ((volatile int*)solved)[row] = 1;
    } else {
        *(float4*)&v[rb] = make_float4(vn[0], vn[1], vn[2], vn[3]);
        *(float4*)&u[rb] = make_float4(un[0], un[1], un[2], un[3]);
        half4 h, l;
        #pragma unroll
        for (int e = 0; e < 4; ++e) {
            float nb = ab[e] + vn[e] - un[e];
            _Float16 hh = (_Float16)nb;
            h[e] = hh;
            l[e] = (_Float16)(nb - (float)hh);
        }
        *(half4*)&bh[rb] = h;
        *(half4*)&bl[rb] = l;
    }
}

// ---------------------------------------------------------------------------
// dec = enc @ w   (1024x1024 * 1024x512 -> 1024x512), fp32, runs once
// ---------------------------------------------------------------------------
__global__ __launch_bounds__(256) void gemm_dec(const float* __restrict__ enc,
                                                const float* __restrict__ w,
                                                float* __restrict__ dec) {
    __shared__ float As[16][68];
    __shared__ float Bs[16][68];
    const int tid = threadIdx.x;
    const int i0 = (blockIdx.x >> 3) * 64, j0 = (blockIdx.x & 7) * 64;
    const int tx = tid & 15, ty = tid >> 4;
    const int la_r = tid >> 2, la_k = (tid & 3) << 2;
    const int lb_k = tid >> 4, lb_j = (tid & 15) << 2;
    float acc[4][4] = {};
    for (int k0 = 0; k0 < MOUT; k0 += 16) {
        float4 a4 = *(const float4*)&enc[(i0 + la_r) * MOUT + k0 + la_k];
        As[la_k + 0][la_r] = a4.x; As[la_k + 1][la_r] = a4.y;
        As[la_k + 2][la_r] = a4.z; As[la_k + 3][la_r] = a4.w;
        float4 b4 = *(const float4*)&w[(k0 + lb_k) * NIN + j0 + lb_j];
        *(float4*)&Bs[lb_k][lb_j] = b4;
        __syncthreads();
        #pragma unroll
        for (int kk = 0; kk < 16; ++kk) {
            float4 a_ = *(const float4*)&As[kk][ty << 2];
            float4 b_ = *(const float4*)&Bs[kk][tx << 2];
            #pragma unroll
            for (int r = 0; r < 4; ++r) {
                float av = r == 0 ? a_.x : r == 1 ? a_.y : r == 2 ? a_.z : a_.w;
                acc[r][0] = fmaf(av, b_.x, acc[r][0]);
                acc[r][1] = fmaf(av, b_.y, acc[r][1]);
                acc[r][2] = fmaf(av, b_.z, acc[r][2]);
                acc[r][3] = fmaf(av, b_.w, acc[r][3]);
            }
        }
        __syncthreads();
    }
    #pragma unroll
    for (int r = 0; r < 4; ++r) {
        float4 o = make_float4(acc[r][0], acc[r][1], acc[r][2], acc[r][3]);
        *(float4*)&dec[(i0 + (ty << 2) + r) * NIN + j0 + (tx << 2)] = o;
    }
}

// ---------------------------------------------------------------------------
extern "C" void kernel_launch(void* const* d_in, const int* in_sizes, int n_in,
                              void* d_out, int out_size, void* d_ws, size_t ws_size,
                              hipStream_t stream) {
    const float* x    = (const float*)d_in[0];
    const float* w    = (const float*)d_in[1];
    const float* Minv = (const float*)d_in[2];

    float* enc = (float*)d_out;          // encoded: 1024*1024
    float* dec = enc + MM;               // decoded: 1024*512

    // ws layout (bytes): adb 4M | v 4M | u 4M | xkp S*4M | f16: bh 2M, bl 2M,
    // Th 2M, Tl 2M | solved 4K+
    float* ws   = (float*)d_ws;
    float* adb  = ws;
    float* v    = ws + (size_t)MM;
    float* u    = ws + 2 * (size_t)MM;
    float* xkp  = ws + 3 * (size_t)MM;

    int S = (ws_size >= ((size_t)(3 + 2) * MM + 2 * MM) * 4 + 8192) ? 2 : 1;
    int kper = MOUT / S;

    _Float16* bh = (_Float16*)(xkp + (size_t)S * MM);
    _Float16* bl = bh + (size_t)MM;
    _Float16* Th = bl + (size_t)MM;
    _Float16* Tl = Th + (size_t)MM;
    int* solved  = (int*)(Tl + (size_t)MM);

    zero_init<<<(MM + 255) / 256, 256, 0, stream>>>(v, u, enc, solved);
    split_minv<<<256, 256, 0, stream>>>(Minv, Th, Tl);
    gemm_adb<<<256, 256, 0, stream>>>(x, w, adb, bh, bl);

    for (int it = 0; it < MAX_ITERS; ++it) {
        gemm_xk<<<256 * S, 256, 0, stream>>>(bh, bl, Th, Tl, xkp, solved, kper);
        update<<<BATCH, 256, 0, stream>>>(adb, xkp, v, u, bh, bl, enc, solved, S);
    }

    gemm_dec<<<128, 256, 0, stream>>>(enc, w, dec);
}